// Round 2
// baseline (376.254 us; speedup 1.0000x reference)
//
#include <hip/hip_runtime.h>
#include <hip/hip_bf16.h>
#include <math.h>

// Problem constants
#define NODES   65536
#define DD      128
#define BM      64          // nodes per block
#define KTOT    640         // [h(128) | mem[other](128) | feat(128) | te(128) | h(128)]
#define BK      32
#define NKT     20          // KTOT/BK
#define NWROWS  512         // padded output rows: [rz_sum(256) | inn(128) | hn(128)]
#define XSTR    56          // LDS row stride (bf16 units): 112B = 16B-aligned, 2-way-bank only
#define WSTR    56
#define WWS_PER_G 327680    // NKT*NWROWS*BK

typedef __bf16 bf16x8 __attribute__((ext_vector_type(8)));
typedef float  f32x4  __attribute__((ext_vector_type(4)));

static __device__ __forceinline__ unsigned short f2bf(float f) {
    __hip_bfloat16 h = __float2bfloat16(f);
    return *reinterpret_cast<unsigned short*>(&h);
}
static __device__ __forceinline__ float sigmoidf_(float x) {
    return 1.0f / (1.0f + __expf(-x));
}

// ---------------------------------------------------------------------------
// Kernel 1: build padded bf16 weights in ws, K-tiled layout:
//   Wws[((g*NKT + kt)*512 + n)*32 + kk]  with k = kt*32+kk over the 640-wide K.
//   rows   0..255 : [Wih[n][0:512] | Whh[n][0:128]]      (r,z: gi+gh fused)
//   rows 256..383 : [Wih[n][0:512] | 0]                  (inn)
//   rows 384..511 : [0             | Whh[n-128][0:128]]  (hn)
// ---------------------------------------------------------------------------
__global__ void prep_w_kernel(const float* __restrict__ Wih0, const float* __restrict__ Whh0,
                              const float* __restrict__ Wih1, const float* __restrict__ Whh1,
                              unsigned short* __restrict__ Wws) {
    int gid = blockIdx.x * 256 + threadIdx.x;
    if (gid >= 2 * WWS_PER_G) return;
    int g   = gid / WWS_PER_G;
    int rem = gid - g * WWS_PER_G;
    int kt  = rem >> 14;             // 512*32 = 16384
    int n   = (rem >> 5) & 511;
    int kk  = rem & 31;
    int k   = kt * 32 + kk;
    const float* Wih = g ? Wih1 : Wih0;
    const float* Whh = g ? Whh1 : Whh0;
    float v;
    if (n < 256) {
        v = (k < 512) ? Wih[n * 512 + k] : Whh[n * 128 + (k - 512)];
    } else if (n < 384) {
        v = (k < 512) ? Wih[n * 512 + k] : 0.0f;
    } else {
        v = (k < 512) ? 0.0f : Whh[(n - 128) * 128 + (k - 512)];
    }
    Wws[gid] = f2bf(v);
}

// ---------------------------------------------------------------------------
// Kernel 2: fused build-X + GEMM (bf16 MFMA 16x16x32) + GRU epilogue.
// grid = (1024, 2): x = node tile (64 nodes), y = g (0=mem GRU, 1=pos GRU)
// block = 512 threads = 8 waves. Wave (wm,wd): wm in {0,1} = 32-row half,
// wd in {0..3} = 32-wide dim slice; wave computes M32 x (4 gates x 32 cols)
// so r/z/inn/hn for a (node,dim) are in the SAME lane -> in-register epilogue.
// ---------------------------------------------------------------------------
__global__ __launch_bounds__(512) void tgn_fused_kernel(
    const int*   __restrict__ n_id,
    const float* __restrict__ memory_,
    const float* __restrict__ pos_mem,
    const float* __restrict__ pos_emb,
    const float* __restrict__ raw_s,
    const float* __restrict__ raw_d,
    const int*   __restrict__ other_s,
    const int*   __restrict__ other_d,
    const int*   __restrict__ t_s,
    const int*   __restrict__ t_d,
    const int*   __restrict__ last_update,
    const float* __restrict__ w_time_mem, const float* __restrict__ b_time_mem,
    const float* __restrict__ w_time_pos, const float* __restrict__ b_time_pos,
    const float* __restrict__ bih_mem, const float* __restrict__ bhh_mem,
    const float* __restrict__ bih_pos, const float* __restrict__ bhh_pos,
    const unsigned short* __restrict__ Wws,
    float* __restrict__ out)
{
    __shared__ __align__(16) unsigned short smem[BM * XSTR + NWROWS * WSTR]; // 64512 B
    __shared__ int   snid[BM];
    __shared__ int   soth[BM];
    __shared__ float sdt[BM];
    __shared__ int   sfeat[BM];

    const int g   = blockIdx.y;
    const int nb  = blockIdx.x;
    const int tid = threadIdx.x;

    const float* mem_g = g ? pos_mem   : memory_;
    const float* wt    = g ? w_time_pos : w_time_mem;
    const float* bt    = g ? b_time_pos : b_time_mem;
    const float* bih   = g ? bih_pos   : bih_mem;
    const float* bhh   = g ? bhh_pos   : bhh_mem;

    // ---- phase 0: per-node scalars ----
    if (tid < BM) {
        int gi   = nb * BM + tid;
        int id   = n_id[gi];
        int ts   = t_s[gi];
        int td   = t_d[gi];
        bool pick = (ts >= td);
        int oth  = pick ? other_s[gi] : other_d[gi];
        int lu   = last_update[id];
        float dt = (float)(pick ? ts : td) - (float)lu;
        int code;
        if (g) code = pick ? id : other_d[gi];          // row into pos_emb
        else   code = pick ? gi : ~gi;                  // >=0: raw_s row, <0: raw_d row ~code
        snid[tid]  = id;
        soth[tid]  = oth;
        sdt[tid]   = dt;
        sfeat[tid] = code;
        if (g == 0) {
            out[2 * (size_t)NODES * DD + gi] = (float)max(ts, td);   // last_up as fp32
        }
    }
    __syncthreads();

    f32x4 acc[16];
    #pragma unroll
    for (int i = 0; i < 16; ++i) acc[i] = (f32x4){0.f, 0.f, 0.f, 0.f};

    unsigned short* Xls = smem;
    unsigned short* Wls = smem + BM * XSTR;
    const unsigned short* wsrc = Wws + (size_t)g * WWS_PER_G;

    const int lane = tid & 63;
    const int wave = tid >> 6;
    const int wm   = wave & 1;        // M half
    const int wd   = wave >> 1;       // dim slice
    const int m0   = wm * 32;
    const int d0   = wd * 32;
    const int q    = lane >> 4;
    const int cl   = lane & 15;

    for (int kt = 0; kt < NKT; ++kt) {
        // ---- stage X tile [64 x 32] (build on the fly) ----
        {
            int i   = tid >> 3;            // node row 0..63
            int c   = (tid & 7) * 4;       // col group 0..28
            int seg = kt >> 2;             // 0:h 1:mem[other] 2:feat 3:te 4:h
            int ks  = (kt & 3) * 32;
            int col = ks + c;              // 0..127 within segment
            float4 v;
            if (seg == 3) {
                float dt = sdt[i];
                float4 wv = *(const float4*)(wt + col);
                float4 bv = *(const float4*)(bt + col);
                v.x = cosf(dt * wv.x + bv.x);
                v.y = cosf(dt * wv.y + bv.y);
                v.z = cosf(dt * wv.z + bv.z);
                v.w = cosf(dt * wv.w + bv.w);
            } else {
                const float* src;
                if (seg == 0 || seg == 4)      src = mem_g + (size_t)snid[i] * DD + col;
                else if (seg == 1)             src = mem_g + (size_t)soth[i] * DD + col;
                else {
                    int code = sfeat[i];
                    if (g)                     src = pos_emb + (size_t)code * DD + col;
                    else if (code >= 0)        src = raw_s + (size_t)code * DD + col;
                    else                       src = raw_d + (size_t)(~code) * DD + col;
                }
                v = *(const float4*)src;
            }
            ushort4 pv;
            pv.x = f2bf(v.x); pv.y = f2bf(v.y); pv.z = f2bf(v.z); pv.w = f2bf(v.w);
            *(ushort4*)(Xls + i * XSTR + c) = pv;

            // ---- stage W tile [512 x 32] = 64 B/row (4x uint4 per thread) ----
            const uint4* s4 = (const uint4*)(wsrc + (size_t)kt * (NWROWS * BK) + tid * BK);
            uint4 w0 = s4[0];
            uint4 w1 = s4[1];
            uint4 w2 = s4[2];
            uint4 w3 = s4[3];
            *(uint4*)(Wls + tid * WSTR)      = w0;
            *(uint4*)(Wls + tid * WSTR + 8)  = w1;
            *(uint4*)(Wls + tid * WSTR + 16) = w2;
            *(uint4*)(Wls + tid * WSTR + 24) = w3;
        }
        __syncthreads();

        // ---- MFMA: A-frag idx=lane&15 (m), k=(lane>>4)*8+j; B-frag same (n,k); W is [N][K] ----
        bf16x8 a0 = *(const bf16x8*)(Xls + (m0 + cl) * XSTR + q * 8);
        bf16x8 a1 = *(const bf16x8*)(Xls + (m0 + 16 + cl) * XSTR + q * 8);
        #pragma unroll
        for (int gate = 0; gate < 4; ++gate) {
            #pragma unroll
            for (int tc = 0; tc < 2; ++tc) {
                int n = gate * 128 + d0 + tc * 16 + cl;
                bf16x8 b = *(const bf16x8*)(Wls + n * WSTR + q * 8);
                acc[(0 * 4 + gate) * 2 + tc] =
                    __builtin_amdgcn_mfma_f32_16x16x32_bf16(a0, b, acc[(0 * 4 + gate) * 2 + tc], 0, 0, 0);
                acc[(1 * 4 + gate) * 2 + tc] =
                    __builtin_amdgcn_mfma_f32_16x16x32_bf16(a1, b, acc[(1 * 4 + gate) * 2 + tc], 0, 0, 0);
            }
        }
        __syncthreads();
    }

    // ---- GRU epilogue, all in-lane. C/D: col = lane&15, row = q*4 + reg ----
    float* outz = out + (size_t)g * NODES * DD;
    #pragma unroll
    for (int tc = 0; tc < 2; ++tc) {
        int d = d0 + tc * 16 + cl;
        float br  = bih[d]       + bhh[d];
        float bz  = bih[128 + d] + bhh[128 + d];
        float bni = bih[256 + d];
        float bnh = bhh[256 + d];
        #pragma unroll
        for (int am = 0; am < 2; ++am) {
            #pragma unroll
            for (int r = 0; r < 4; ++r) {
                int il = m0 + am * 16 + q * 4 + r;           // node row in block
                float rs = acc[(am * 4 + 0) * 2 + tc][r] + br;
                float zs = acc[(am * 4 + 1) * 2 + tc][r] + bz;
                float in_ = acc[(am * 4 + 2) * 2 + tc][r] + bni;
                float hn_ = acc[(am * 4 + 3) * 2 + tc][r] + bnh;
                float rg = sigmoidf_(rs);
                float zg = sigmoidf_(zs);
                float nv = tanhf(in_ + rg * hn_);
                float h  = mem_g[(size_t)snid[il] * DD + d];
                outz[(size_t)(nb * BM + il) * DD + d] = (1.0f - zg) * nv + zg * h;
            }
        }
    }
}

// ---------------------------------------------------------------------------
extern "C" void kernel_launch(void* const* d_in, const int* in_sizes, int n_in,
                              void* d_out, int out_size, void* d_ws, size_t ws_size,
                              hipStream_t stream) {
    const int*   n_id        = (const int*)  d_in[0];
    const float* memory_     = (const float*)d_in[1];
    const float* pos_mem     = (const float*)d_in[2];
    const float* pos_emb     = (const float*)d_in[3];
    const float* raw_s       = (const float*)d_in[4];
    const float* raw_d       = (const float*)d_in[5];
    const int*   other_s     = (const int*)  d_in[6];
    const int*   other_d     = (const int*)  d_in[7];
    const int*   t_s         = (const int*)  d_in[8];
    const int*   t_d         = (const int*)  d_in[9];
    const int*   last_update = (const int*)  d_in[10];
    const float* w_time_mem  = (const float*)d_in[11];
    const float* b_time_mem  = (const float*)d_in[12];
    const float* w_time_pos  = (const float*)d_in[13];
    const float* b_time_pos  = (const float*)d_in[14];
    const float* Wih_mem     = (const float*)d_in[15];
    const float* Whh_mem     = (const float*)d_in[16];
    const float* bih_mem     = (const float*)d_in[17];
    const float* bhh_mem     = (const float*)d_in[18];
    const float* Wih_pos     = (const float*)d_in[19];
    const float* Whh_pos     = (const float*)d_in[20];
    const float* bih_pos     = (const float*)d_in[21];
    const float* bhh_pos     = (const float*)d_in[22];

    unsigned short* Wws = (unsigned short*)d_ws;   // 2*327680 bf16 = 1.28 MB
    float* out = (float*)d_out;

    prep_w_kernel<<<(2 * WWS_PER_G + 255) / 256, 256, 0, stream>>>(
        Wih_mem, Whh_mem, Wih_pos, Whh_pos, Wws);

    dim3 grid(NODES / BM, 2);
    tgn_fused_kernel<<<grid, 512, 0, stream>>>(
        n_id, memory_, pos_mem, pos_emb, raw_s, raw_d,
        other_s, other_d, t_s, t_d, last_update,
        w_time_mem, b_time_mem, w_time_pos, b_time_pos,
        bih_mem, bhh_mem, bih_pos, bhh_pos,
        Wws, out);
}

// Round 3
// 347.206 us; speedup vs baseline: 1.0837x; 1.0837x over previous
//
#include <hip/hip_runtime.h>
#include <hip/hip_bf16.h>
#include <math.h>

// Problem constants
#define NODES   65536
#define DD      128
#define BM      64          // nodes per block
#define BK      32          // K per stage
#define NST     16          // X stages: K=512 of [h | mem[oth] | feat | te]
#define NWT     20          // W k-tiles: 16 Wih (K=512) + 4 Whh (K=128)
#define NSUB    24          // 384 N-rows / 16 per subtile
#define WTILE_STRIDE (NSUB * 64 * 8)     // 12288 shorts per W k-tile
#define WG_STRIDE    (NWT * WTILE_STRIDE) // 245760 shorts per GRU

typedef __bf16 bf16x8 __attribute__((ext_vector_type(8)));
typedef float  f32x4  __attribute__((ext_vector_type(4)));

static __device__ __forceinline__ unsigned short f2bf(float f) {
    __hip_bfloat16 h = __float2bfloat16(f);
    return *reinterpret_cast<unsigned short*>(&h);
}
static __device__ __forceinline__ float sigmoidf_(float x) {
    return 1.0f / (1.0f + __expf(-x));
}

// ---------------------------------------------------------------------------
// Kernel 1: pre-swizzle W into per-lane MFMA B-fragment order (bf16) in ws.
//   Row space n=0..383: [r(128) | z(128) | n-gate(128)] (Wih and Whh share it).
//   k-tiles 0..15: Wih cols kt*32..+31 ; k-tiles 16..19: Whh cols (kt-16)*32..+31.
//   Element (g,kt,t,lane,j): n = t*16 + (lane&15), k = (lane>>4)*8 + j within tile.
//   Layout: Wws[((g*NWT + kt)*NSUB + t)*512 + lane*8 + j] -> each lane's B-frag
//   is one contiguous 16 B load; a wave's 64 lanes load 1 KB coalesced (L2-hot).
// ---------------------------------------------------------------------------
__global__ void prep_w_kernel(const float* __restrict__ Wih0, const float* __restrict__ Whh0,
                              const float* __restrict__ Wih1, const float* __restrict__ Whh1,
                              unsigned short* __restrict__ Wws) {
    int gid = blockIdx.x * 256 + threadIdx.x;
    if (gid >= 2 * WG_STRIDE) return;
    int g   = gid / WG_STRIDE;
    int r   = gid - g * WG_STRIDE;
    int kt  = r / WTILE_STRIDE;
    int r2  = r - kt * WTILE_STRIDE;
    int t   = r2 >> 9;                 // subtile 0..23
    int l8  = r2 & 511;
    int lane = l8 >> 3, j = l8 & 7;
    int cl  = lane & 15, q = lane >> 4;
    int n   = t * 16 + cl;
    const float* Wih = g ? Wih1 : Wih0;
    const float* Whh = g ? Whh1 : Whh0;
    float v;
    if (kt < 16) v = Wih[n * 512 + kt * 32 + q * 8 + j];
    else         v = Whh[n * 128 + (kt - 16) * 32 + q * 8 + j];
    Wws[gid] = f2bf(v);
}

// ---------------------------------------------------------------------------
// Kernel 2: fused build-X + zero-waste GEMM + GRU epilogue.
// grid = (1024, 2): x = node tile (64 nodes), y = g (0=mem GRU, 1=pos GRU).
// 512 threads = 8 waves: wave (wm,wd), wm = 32-row half, wd = 32-dim slice.
// Per stage st (0..15): X tile [64 x 32] (bf16, double-buffered LDS), Wih tile
// kt=st feeds slots {r,z,inn}; for st<4 the SAME A-frags (h columns) also feed
// Whh tile kt=16+st, slots {r,z,hn}. r/z accs receive ir+hr / iz+hz directly.
// B-fragments come straight from L2 (pre-swizzled ws) — no W in LDS, 1 barrier/stage.
// ---------------------------------------------------------------------------
__global__ __launch_bounds__(512, 4) void tgn_fused_kernel(
    const int*   __restrict__ n_id,
    const float* __restrict__ memory_,
    const float* __restrict__ pos_mem,
    const float* __restrict__ pos_emb,
    const float* __restrict__ raw_s,
    const float* __restrict__ raw_d,
    const int*   __restrict__ other_s,
    const int*   __restrict__ other_d,
    const int*   __restrict__ t_s,
    const int*   __restrict__ t_d,
    const int*   __restrict__ last_update,
    const float* __restrict__ w_time_mem, const float* __restrict__ b_time_mem,
    const float* __restrict__ w_time_pos, const float* __restrict__ b_time_pos,
    const float* __restrict__ bih_mem, const float* __restrict__ bhh_mem,
    const float* __restrict__ bih_pos, const float* __restrict__ bhh_pos,
    const unsigned short* __restrict__ Wws,
    float* __restrict__ out)
{
    __shared__ __align__(16) unsigned short Xls[2][BM * BK];   // 2 x 4 KB
    __shared__ int   snid[BM];
    __shared__ int   soth[BM];
    __shared__ float sdt[BM];
    __shared__ int   sfeat[BM];

    const int g   = blockIdx.y;
    const int nb  = blockIdx.x;
    const int tid = threadIdx.x;

    const float* mem_g = g ? pos_mem    : memory_;
    const float* wt    = g ? w_time_pos : w_time_mem;
    const float* bt    = g ? b_time_pos : b_time_mem;
    const float* bih   = g ? bih_pos    : bih_mem;
    const float* bhh   = g ? bhh_pos    : bhh_mem;

    // ---- phase 0: per-node scalars ----
    if (tid < BM) {
        int gi   = nb * BM + tid;
        int id   = n_id[gi];
        int ts   = t_s[gi];
        int td   = t_d[gi];
        bool pick = (ts >= td);
        int oth  = pick ? other_s[gi] : other_d[gi];
        int lu   = last_update[id];
        float dt = (float)(pick ? ts : td) - (float)lu;
        int code;
        if (g) code = pick ? id : other_d[gi];          // row into pos_emb
        else   code = pick ? gi : ~gi;                  // >=0: raw_s row, <0: raw_d row ~code
        snid[tid]  = id;
        soth[tid]  = oth;
        sdt[tid]   = dt;
        sfeat[tid] = code;
        if (g == 0) {
            out[2 * (size_t)NODES * DD + gi] = (float)max(ts, td);   // last_up as fp32
        }
    }

    f32x4 acc[16];
    #pragma unroll
    for (int i = 0; i < 16; ++i) acc[i] = (f32x4){0.f, 0.f, 0.f, 0.f};

    const int lane = tid & 63;
    const int wave = tid >> 6;
    const int wm   = wave & 1;        // M half
    const int wd   = wave >> 1;       // dim slice
    const int m0   = wm * 32;
    const int d0   = wd * 32;
    const int q    = lane >> 4;
    const int cl   = lane & 15;

    // staging mapping: thread -> (row, 4-col group)
    const int si = tid >> 3;
    const int sc = (tid & 7) * 4;

    // W fragment bases (L2-resident, pre-swizzled): subtile t rows = t*16..t*16+15
    const unsigned short* wbase = Wws + (size_t)g * WG_STRIDE + lane * 8;
    const int tR = 2 * wd;          // r rows    (n = d0..d0+31)
    const int tZ = 8 + 2 * wd;      // z rows
    const int tN = 16 + 2 * wd;     // n-gate rows

    // acc slot index: (am*4 + slot)*2 + tc ; slot 0=r,1=z,2=inn,3=hn
    #define MFMA(s, tc, a, b) \
        acc[((s)) * 2 + (tc)] = __builtin_amdgcn_mfma_f32_16x16x32_bf16((a), (b), acc[((s)) * 2 + (tc)], 0, 0, 0); \
        acc[(4 + (s)) * 2 + (tc)] = __builtin_amdgcn_mfma_f32_16x16x32_bf16((a1), (b), acc[(4 + (s)) * 2 + (tc)], 0, 0, 0);

    // ---- stage helper (macro-ish lambda) ----
    auto stageX = [&](int st, unsigned short* buf) {
        int seg = st >> 2;             // 0:h 1:mem[oth] 2:feat 3:te
        int col = (st & 3) * 32 + sc;  // 0..127 within segment
        float4 v;
        if (seg == 3) {
            float dt = sdt[si];
            float4 wv = *(const float4*)(wt + col);
            float4 bv = *(const float4*)(bt + col);
            v.x = cosf(dt * wv.x + bv.x);
            v.y = cosf(dt * wv.y + bv.y);
            v.z = cosf(dt * wv.z + bv.z);
            v.w = cosf(dt * wv.w + bv.w);
        } else {
            const float* src;
            if (seg == 0)            src = mem_g + (size_t)snid[si] * DD + col;
            else if (seg == 1)       src = mem_g + (size_t)soth[si] * DD + col;
            else {
                int code = sfeat[si];
                if (g)               src = pos_emb + (size_t)code * DD + col;
                else if (code >= 0)  src = raw_s + (size_t)code * DD + col;
                else                 src = raw_d + (size_t)(~code) * DD + col;
            }
            v = *(const float4*)src;
        }
        ushort4 pv;
        pv.x = f2bf(v.x); pv.y = f2bf(v.y); pv.z = f2bf(v.z); pv.w = f2bf(v.w);
        *(ushort4*)(buf + si * BK + sc) = pv;
    };

    __syncthreads();                  // phase-0 scalars visible
    stageX(0, Xls[0]);
    __syncthreads();

    for (int st = 0; st < NST; ++st) {
        unsigned short* cur = Xls[st & 1];
        // A-frags: lane (cl,q) -> row m0+cl (and +16), k = q*8..+7 ; conflict-free
        bf16x8 a0 = *(const bf16x8*)(cur + (m0 + cl) * BK + q * 8);
        bf16x8 a1 = *(const bf16x8*)(cur + (m0 + 16 + cl) * BK + q * 8);
        if (st < NST - 1) stageX(st + 1, Xls[(st + 1) & 1]);
        __syncthreads();

        const unsigned short* wk = wbase + (size_t)st * WTILE_STRIDE;
        bf16x8 bR0 = *(const bf16x8*)(wk + (tR    ) * 512);
        bf16x8 bR1 = *(const bf16x8*)(wk + (tR + 1) * 512);
        bf16x8 bZ0 = *(const bf16x8*)(wk + (tZ    ) * 512);
        bf16x8 bZ1 = *(const bf16x8*)(wk + (tZ + 1) * 512);
        bf16x8 bN0 = *(const bf16x8*)(wk + (tN    ) * 512);
        bf16x8 bN1 = *(const bf16x8*)(wk + (tN + 1) * 512);
        MFMA(0, 0, a0, bR0)  MFMA(0, 1, a0, bR1)
        MFMA(1, 0, a0, bZ0)  MFMA(1, 1, a0, bZ1)
        MFMA(2, 0, a0, bN0)  MFMA(2, 1, a0, bN1)

        if (st < 4) {   // Whh tiles reuse the h A-frags (X cols 0..127)
            const unsigned short* wh = wbase + (size_t)(16 + st) * WTILE_STRIDE;
            bf16x8 cR0 = *(const bf16x8*)(wh + (tR    ) * 512);
            bf16x8 cR1 = *(const bf16x8*)(wh + (tR + 1) * 512);
            bf16x8 cZ0 = *(const bf16x8*)(wh + (tZ    ) * 512);
            bf16x8 cZ1 = *(const bf16x8*)(wh + (tZ + 1) * 512);
            bf16x8 cN0 = *(const bf16x8*)(wh + (tN    ) * 512);
            bf16x8 cN1 = *(const bf16x8*)(wh + (tN + 1) * 512);
            MFMA(0, 0, a0, cR0)  MFMA(0, 1, a0, cR1)
            MFMA(1, 0, a0, cZ0)  MFMA(1, 1, a0, cZ1)
            MFMA(3, 0, a0, cN0)  MFMA(3, 1, a0, cN1)
        }
    }
    #undef MFMA

    // ---- GRU epilogue, in-lane. C/D: col(n)=lane&15, row(m)=q*4+reg ----
    float* outz = out + (size_t)g * NODES * DD;
    #pragma unroll
    for (int tc = 0; tc < 2; ++tc) {
        int d = d0 + tc * 16 + cl;
        float br  = bih[d]       + bhh[d];
        float bz  = bih[128 + d] + bhh[128 + d];
        float bni = bih[256 + d];
        float bnh = bhh[256 + d];
        #pragma unroll
        for (int am = 0; am < 2; ++am) {
            #pragma unroll
            for (int r = 0; r < 4; ++r) {
                int il = m0 + am * 16 + q * 4 + r;           // node row in block
                float rs  = acc[(am * 4 + 0) * 2 + tc][r] + br;
                float zs  = acc[(am * 4 + 1) * 2 + tc][r] + bz;
                float in_ = acc[(am * 4 + 2) * 2 + tc][r] + bni;
                float hn_ = acc[(am * 4 + 3) * 2 + tc][r] + bnh;
                float rg = sigmoidf_(rs);
                float zg = sigmoidf_(zs);
                float nv = tanhf(in_ + rg * hn_);
                float h  = mem_g[(size_t)snid[il] * DD + d];
                outz[(size_t)(nb * BM + il) * DD + d] = (1.0f - zg) * nv + zg * h;
            }
        }
    }
}

// ---------------------------------------------------------------------------
extern "C" void kernel_launch(void* const* d_in, const int* in_sizes, int n_in,
                              void* d_out, int out_size, void* d_ws, size_t ws_size,
                              hipStream_t stream) {
    const int*   n_id        = (const int*)  d_in[0];
    const float* memory_     = (const float*)d_in[1];
    const float* pos_mem     = (const float*)d_in[2];
    const float* pos_emb     = (const float*)d_in[3];
    const float* raw_s       = (const float*)d_in[4];
    const float* raw_d       = (const float*)d_in[5];
    const int*   other_s     = (const int*)  d_in[6];
    const int*   other_d     = (const int*)  d_in[7];
    const int*   t_s         = (const int*)  d_in[8];
    const int*   t_d         = (const int*)  d_in[9];
    const int*   last_update = (const int*)  d_in[10];
    const float* w_time_mem  = (const float*)d_in[11];
    const float* b_time_mem  = (const float*)d_in[12];
    const float* w_time_pos  = (const float*)d_in[13];
    const float* b_time_pos  = (const float*)d_in[14];
    const float* Wih_mem     = (const float*)d_in[15];
    const float* Whh_mem     = (const float*)d_in[16];
    const float* bih_mem     = (const float*)d_in[17];
    const float* bhh_mem     = (const float*)d_in[18];
    const float* Wih_pos     = (const float*)d_in[19];
    const float* Whh_pos     = (const float*)d_in[20];
    const float* bih_pos     = (const float*)d_in[21];
    const float* bhh_pos     = (const float*)d_in[22];

    unsigned short* Wws = (unsigned short*)d_ws;   // 2*245760 bf16 = 983 KB
    float* out = (float*)d_out;

    prep_w_kernel<<<(2 * WG_STRIDE + 255) / 256, 256, 0, stream>>>(
        Wih_mem, Whh_mem, Wih_pos, Whh_pos, Wws);

    dim3 grid(NODES / BM, 2);
    tgn_fused_kernel<<<grid, 512, 0, stream>>>(
        n_id, memory_, pos_mem, pos_emb, raw_s, raw_d,
        other_s, other_d, t_s, t_d, last_update,
        w_time_mem, b_time_mem, w_time_pos, b_time_pos,
        bih_mem, bhh_mem, bih_pos, bhh_pos,
        Wws, out);
}

// Round 4
// 311.112 us; speedup vs baseline: 1.2094x; 1.1160x over previous
//
#include <hip/hip_runtime.h>
#include <hip/hip_bf16.h>
#include <math.h>

// Problem constants
#define NODES   65536
#define DD      128
#define BM      64          // nodes per block
#define NST     16          // K stages of 32: X = [h(128)|mem[oth](128)|feat(128)|te(128)]
#define NSUB    24          // 384 N-rows / 16 per subtile
#define WTILE_STRIDE (NSUB * 64 * 8)      // 12288 shorts per W k-tile
#define WG_STRIDE    (20 * WTILE_STRIDE)  // 16 Wih + 4 Whh k-tiles per GRU
#define XW      544         // X LDS row stride in shorts (272 words, even bank spread)

typedef __bf16 bf16x8 __attribute__((ext_vector_type(8)));
typedef float  f32x4  __attribute__((ext_vector_type(4)));

static __device__ __forceinline__ unsigned short f2bf(float f) {
    union { float f; unsigned u; } v; v.f = f;
    return (unsigned short)((v.u + 0x8000u) >> 16);      // round-half-up bf16
}
static __device__ __forceinline__ float fastcos(float x) {
    float r = x * 0.15915494309189535f;                   // x / (2*pi)
    r = r - floorf(r);                                    // range-reduce to [0,1)
    return __builtin_amdgcn_cosf(r);                      // v_cos_f32 (revolutions)
}
static __device__ __forceinline__ float fsigmoid(float x) {
    return 1.0f / (1.0f + __expf(-x));
}
static __device__ __forceinline__ float ftanh(float x) {
    float ax = fabsf(x);
    float t  = __expf(-2.0f * ax);
    float th = 1.0f - 2.0f * t / (1.0f + t);
    return copysignf(th, x);
}

// ---------------------------------------------------------------------------
// Kernel 1: pre-swizzle W into per-lane MFMA B-fragment order (bf16) in ws.
//   N-row space n=0..383: [r(128) | z(128) | n-gate(128)].
//   k-tiles 0..15: Wih cols kt*32..+31 ; k-tiles 16..19: Whh cols (kt-16)*32..+31.
//   Wws[((g*20 + kt)*NSUB + t)*512 + lane*8 + j]: n = t*16+(lane&15),
//   k = (lane>>4)*8+j. Each lane's B-frag = one 16 B load, wave = 1 KB coalesced.
// ---------------------------------------------------------------------------
__global__ void prep_w_kernel(const float* __restrict__ Wih0, const float* __restrict__ Whh0,
                              const float* __restrict__ Wih1, const float* __restrict__ Whh1,
                              unsigned short* __restrict__ Wws) {
    int gid = blockIdx.x * 256 + threadIdx.x;
    if (gid >= 2 * WG_STRIDE) return;
    int g   = gid / WG_STRIDE;
    int r   = gid - g * WG_STRIDE;
    int kt  = r / WTILE_STRIDE;
    int r2  = r - kt * WTILE_STRIDE;
    int t   = r2 >> 9;                 // subtile 0..23
    int l8  = r2 & 511;
    int lane = l8 >> 3, j = l8 & 7;
    int cl  = lane & 15, q = lane >> 4;
    int n   = t * 16 + cl;
    const float* Wih = g ? Wih1 : Wih0;
    const float* Whh = g ? Whh1 : Whh0;
    float v;
    if (kt < 16) v = Wih[n * 512 + kt * 32 + q * 8 + j];
    else         v = Whh[n * 128 + (kt - 16) * 32 + q * 8 + j];
    Wws[gid] = f2bf(v);
}

// ---------------------------------------------------------------------------
// Kernel 2: stage full X once -> barrier-free MFMA K-loop -> GRU epilogue.
// grid = (1024, 2); 512 threads = 8 waves. Wave w owns M=64 x N-slice d in
// [w*16, w*16+16) for all 4 gate accumulators (r,z,inn,hn in the SAME lane).
// B-frags: each read exactly once per block, straight from L2 (pre-swizzled).
// A-frags: ds_read_b128 from the 70 KB X tile. No barriers in the K-loop.
// ---------------------------------------------------------------------------
__global__ __launch_bounds__(512, 4) void tgn_fused_kernel(
    const int*   __restrict__ n_id,
    const float* __restrict__ memory_,
    const float* __restrict__ pos_mem,
    const float* __restrict__ pos_emb,
    const float* __restrict__ raw_s,
    const float* __restrict__ raw_d,
    const int*   __restrict__ other_s,
    const int*   __restrict__ other_d,
    const int*   __restrict__ t_s,
    const int*   __restrict__ t_d,
    const int*   __restrict__ last_update,
    const float* __restrict__ w_time_mem, const float* __restrict__ b_time_mem,
    const float* __restrict__ w_time_pos, const float* __restrict__ b_time_pos,
    const float* __restrict__ bih_mem, const float* __restrict__ bhh_mem,
    const float* __restrict__ bih_pos, const float* __restrict__ bhh_pos,
    const unsigned short* __restrict__ Wws,
    float* __restrict__ out)
{
    __shared__ __align__(16) unsigned short X[BM * XW];   // 69632 B
    __shared__ int   snid[BM];
    __shared__ int   soth[BM];
    __shared__ float sdt[BM];
    __shared__ int   sfeat[BM];

    const int g   = blockIdx.y;
    const int nb  = blockIdx.x;
    const int tid = threadIdx.x;
    const int lane = tid & 63;
    const int wave = tid >> 6;

    const float* mem_g = g ? pos_mem    : memory_;
    const float* wt    = g ? w_time_pos : w_time_mem;
    const float* bt    = g ? b_time_pos : b_time_mem;
    const float* bih   = g ? bih_pos    : bih_mem;
    const float* bhh   = g ? bhh_pos    : bhh_mem;

    // ---- phase 0: per-node scalars ----
    if (tid < BM) {
        int gi   = nb * BM + tid;
        int id   = n_id[gi];
        int ts   = t_s[gi];
        int td   = t_d[gi];
        bool pick = (ts >= td);
        int oth  = pick ? other_s[gi] : other_d[gi];
        int lu   = last_update[id];
        float dt = (float)(pick ? ts : td) - (float)lu;
        int code;
        if (g) code = pick ? id : other_d[gi];          // row into pos_emb
        else   code = pick ? gi : ~gi;                  // >=0: raw_s row, <0: raw_d row ~code
        snid[tid]  = id;
        soth[tid]  = oth;
        sdt[tid]   = dt;
        sfeat[tid] = code;
        if (g == 0) {
            out[2 * (size_t)NODES * DD + gi] = (float)max(ts, td);   // last_up as fp32
        }
    }
    __syncthreads();

    // ---- stage full X tile: row = lane, wave picks a 64-col chunk ----
    // waves 0-5: global fp32 -> bf16 (h | mem[oth] | feat), waves 6-7: time enc
    {
        int row = lane;
        if (wave >= 6) {
            float dt = sdt[row];
            int c0 = (wave - 6) * 64;
            #pragma unroll
            for (int i = 0; i < 16; ++i) {
                int c = c0 + i * 4;
                float4 wv = *(const float4*)(wt + c);
                float4 bv = *(const float4*)(bt + c);
                ushort4 pv;
                pv.x = f2bf(fastcos(dt * wv.x + bv.x));
                pv.y = f2bf(fastcos(dt * wv.y + bv.y));
                pv.z = f2bf(fastcos(dt * wv.z + bv.z));
                pv.w = f2bf(fastcos(dt * wv.w + bv.w));
                *(ushort4*)(X + row * XW + 384 + c) = pv;
            }
        } else {
            int seg = wave >> 1;            // 0:h 1:mem[oth] 2:feat
            int c0  = (wave & 1) * 64;
            const float* src;
            if (seg == 0)      src = mem_g + (size_t)snid[row] * DD + c0;
            else if (seg == 1) src = mem_g + (size_t)soth[row] * DD + c0;
            else {
                int code = sfeat[row];
                if (g)              src = pos_emb + (size_t)code * DD + c0;
                else if (code >= 0) src = raw_s + (size_t)code * DD + c0;
                else                src = raw_d + (size_t)(~code) * DD + c0;
            }
            #pragma unroll
            for (int i = 0; i < 16; ++i) {
                float4 v = *(const float4*)(src + i * 4);
                ushort4 pv;
                pv.x = f2bf(v.x); pv.y = f2bf(v.y); pv.z = f2bf(v.z); pv.w = f2bf(v.w);
                *(ushort4*)(X + row * XW + seg * 128 + c0 + i * 4) = pv;
            }
        }
    }
    __syncthreads();   // the ONLY barrier before the K-loop

    // ---- barrier-free K-loop ----
    f32x4 acc[16];     // [j(m-tile 0..3)][slot 0=r,1=z,2=inn,3=hn]
    #pragma unroll
    for (int i = 0; i < 16; ++i) acc[i] = (f32x4){0.f, 0.f, 0.f, 0.f};

    const int q  = lane >> 4;
    const int cl = lane & 15;
    const unsigned short* wbase = Wws + (size_t)g * WG_STRIDE + lane * 8;
    const int tR = wave, tZ = 8 + wave, tN = 16 + wave;

    #pragma unroll
    for (int st = 0; st < NST; ++st) {
        bf16x8 a[4];
        #pragma unroll
        for (int j = 0; j < 4; ++j)
            a[j] = *(const bf16x8*)(X + (j * 16 + cl) * XW + st * 32 + q * 8);

        const unsigned short* wk = wbase + (size_t)st * WTILE_STRIDE;
        bf16x8 bR = *(const bf16x8*)(wk + tR * 512);
        bf16x8 bZ = *(const bf16x8*)(wk + tZ * 512);
        bf16x8 bN = *(const bf16x8*)(wk + tN * 512);
        #pragma unroll
        for (int j = 0; j < 4; ++j) {
            acc[j * 4 + 0] = __builtin_amdgcn_mfma_f32_16x16x32_bf16(a[j], bR, acc[j * 4 + 0], 0, 0, 0);
            acc[j * 4 + 1] = __builtin_amdgcn_mfma_f32_16x16x32_bf16(a[j], bZ, acc[j * 4 + 1], 0, 0, 0);
            acc[j * 4 + 2] = __builtin_amdgcn_mfma_f32_16x16x32_bf16(a[j], bN, acc[j * 4 + 2], 0, 0, 0);
        }
        if (st < 4) {   // Whh k-tiles share the h A-frags (X cols 0..127)
            const unsigned short* wh = wbase + (size_t)(16 + st) * WTILE_STRIDE;
            bf16x8 cR = *(const bf16x8*)(wh + tR * 512);
            bf16x8 cZ = *(const bf16x8*)(wh + tZ * 512);
            bf16x8 cN = *(const bf16x8*)(wh + tN * 512);
            #pragma unroll
            for (int j = 0; j < 4; ++j) {
                acc[j * 4 + 0] = __builtin_amdgcn_mfma_f32_16x16x32_bf16(a[j], cR, acc[j * 4 + 0], 0, 0, 0);
                acc[j * 4 + 1] = __builtin_amdgcn_mfma_f32_16x16x32_bf16(a[j], cZ, acc[j * 4 + 1], 0, 0, 0);
                acc[j * 4 + 3] = __builtin_amdgcn_mfma_f32_16x16x32_bf16(a[j], cN, acc[j * 4 + 3], 0, 0, 0);
            }
        }
    }

    // ---- GRU epilogue, in-lane. C/D: col(n)=lane&15, row(m)=q*4+reg ----
    float* outz = out + (size_t)g * NODES * DD;
    const int d = wave * 16 + cl;
    float br  = bih[d]       + bhh[d];
    float bz  = bih[128 + d] + bhh[128 + d];
    float bni = bih[256 + d];
    float bnh = bhh[256 + d];
    #pragma unroll
    for (int j = 0; j < 4; ++j) {
        #pragma unroll
        for (int r = 0; r < 4; ++r) {
            int il = j * 16 + q * 4 + r;                 // node row in block
            float rs  = acc[j * 4 + 0][r] + br;
            float zs  = acc[j * 4 + 1][r] + bz;
            float in_ = acc[j * 4 + 2][r] + bni;
            float hn_ = acc[j * 4 + 3][r] + bnh;
            float rg = fsigmoid(rs);
            float zg = fsigmoid(zs);
            float nv = ftanh(in_ + rg * hn_);
            float h  = mem_g[(size_t)snid[il] * DD + d];
            outz[(size_t)(nb * BM + il) * DD + d] = (1.0f - zg) * nv + zg * h;
        }
    }
}

// ---------------------------------------------------------------------------
extern "C" void kernel_launch(void* const* d_in, const int* in_sizes, int n_in,
                              void* d_out, int out_size, void* d_ws, size_t ws_size,
                              hipStream_t stream) {
    const int*   n_id        = (const int*)  d_in[0];
    const float* memory_     = (const float*)d_in[1];
    const float* pos_mem     = (const float*)d_in[2];
    const float* pos_emb     = (const float*)d_in[3];
    const float* raw_s       = (const float*)d_in[4];
    const float* raw_d       = (const float*)d_in[5];
    const int*   other_s     = (const int*)  d_in[6];
    const int*   other_d     = (const int*)  d_in[7];
    const int*   t_s         = (const int*)  d_in[8];
    const int*   t_d         = (const int*)  d_in[9];
    const int*   last_update = (const int*)  d_in[10];
    const float* w_time_mem  = (const float*)d_in[11];
    const float* b_time_mem  = (const float*)d_in[12];
    const float* w_time_pos  = (const float*)d_in[13];
    const float* b_time_pos  = (const float*)d_in[14];
    const float* Wih_mem     = (const float*)d_in[15];
    const float* Whh_mem     = (const float*)d_in[16];
    const float* bih_mem     = (const float*)d_in[17];
    const float* bhh_mem     = (const float*)d_in[18];
    const float* Wih_pos     = (const float*)d_in[19];
    const float* Whh_pos     = (const float*)d_in[20];
    const float* bih_pos     = (const float*)d_in[21];
    const float* bhh_pos     = (const float*)d_in[22];

    unsigned short* Wws = (unsigned short*)d_ws;   // 2*245760 bf16 = 983 KB
    float* out = (float*)d_out;

    prep_w_kernel<<<(2 * WG_STRIDE + 255) / 256, 256, 0, stream>>>(
        Wih_mem, Whh_mem, Wih_pos, Whh_pos, Wws);

    dim3 grid(NODES / BM, 2);
    tgn_fused_kernel<<<grid, 512, 0, stream>>>(
        n_id, memory_, pos_mem, pos_emb, raw_s, raw_d,
        other_s, other_d, t_s, t_d, last_update,
        w_time_mem, b_time_mem, w_time_pos, b_time_pos,
        bih_mem, bhh_mem, bih_pos, bhh_pos,
        Wws, out);
}